// Round 12
// baseline (296.766 us; speedup 1.0000x reference)
//
#include <hip/hip_runtime.h>
#include <hip/hip_bf16.h>
#include <cstdint>

#define NC 28
#define HW 65536   // 256*256
#define ROWW 256
#define COLW 310
#define BATCH 16

typedef __hip_bfloat16 bf16;

__device__ __forceinline__ float bflo(unsigned int u) { return __uint_as_float(u << 16); }
__device__ __forceinline__ float bfhi(unsigned int u) { return __uint_as_float(u & 0xffff0000u); }
__device__ __forceinline__ unsigned int pk2(float lo, float hi) {
    unsigned short l = __builtin_bit_cast(unsigned short, __float2bfloat16(lo));
    unsigned short h = __builtin_bit_cast(unsigned short, __float2bfloat16(hi));
    return (unsigned int)l | ((unsigned int)h << 16);
}
__device__ __forceinline__ unsigned int pkh(float lo, float hi) {
    auto h = __builtin_amdgcn_cvt_pkrtz(lo, hi);
    return __builtin_bit_cast(unsigned int, h);
}
__device__ __forceinline__ float h2f_lo(unsigned int u) {
    return (float)__builtin_bit_cast(_Float16, (unsigned short)(u & 0xffffu));
}
__device__ __forceinline__ float h2f_hi(unsigned int u) {
    return (float)__builtin_bit_cast(_Float16, (unsigned short)(u >> 16));
}
// packed 2xf16 fma, weight in SGPR (block-uniform)
__device__ __forceinline__ void pkfma16(unsigned int& acc, unsigned int w, unsigned int x) {
    asm("v_pk_fma_f16 %0, %1, %2, %0" : "+v"(acc) : "s"(w), "v"(x));
}
// packed 2xf16 fma, weight in VGPR (per-lane)
__device__ __forceinline__ void pkfma16v(unsigned int& acc, unsigned int w, unsigned int x) {
    asm("v_pk_fma_f16 %0, %1, %2, %0" : "+v"(acc) : "v"(w), "v"(x));
}

#define REP28A(X) X(0) X(1) X(2) X(3) X(4) X(5) X(6) X(7) X(8) X(9) X(10) X(11) X(12) X(13) \
                  X(14) X(15) X(16) X(17) X(18) X(19) X(20) X(21) X(22) X(23) X(24) X(25) X(26) X(27)
#define REP28B(X) X(0) X(1) X(2) X(3) X(4) X(5) X(6) X(7) X(8) X(9) X(10) X(11) X(12) X(13) \
                  X(14) X(15) X(16) X(17) X(18) X(19) X(20) X(21) X(22) X(23) X(24) X(25) X(26) X(27)

// hdr layout (uint words):
//   [0..783]     w1h[c*28+o]  f16 pair (mm,pv)   (transposed)
//   [784..1567]  w2h[o*28+m]
//   [1568..1595] b1h[o]
//   [1596..1623] b2h[o]
//   [1624..2323] dwh[c*25+k]
//   [2324..2351] dbh[c]
//   [2352..2661] alpha[col] (float bits)
#define HDR_BYTES 16384

// ---------------- K0: prep ----------------
__global__ void k0_prep(const float* __restrict__ w1mm, const float* __restrict__ w1pv,
                        const float* __restrict__ w2mm, const float* __restrict__ w2pv,
                        const float* __restrict__ b1mm, const float* __restrict__ b1pv,
                        const float* __restrict__ b2mm, const float* __restrict__ b2pv,
                        const float* __restrict__ dwm,  const float* __restrict__ dwp,
                        const float* __restrict__ dbm,  const float* __restrict__ dbp,
                        unsigned int* __restrict__ hdr)
{
    int t = threadIdx.x;
    for (int e = t; e < 784; e += 256) {
        int c = e / 28, o = e - c * 28;
        hdr[e]       = pkh(w1mm[o * 28 + c], w1pv[o * 28 + c]);
        hdr[784 + e] = pkh(w2mm[e], w2pv[e]);
    }
    if (t < 28) {
        hdr[1568 + t] = pkh(b1mm[t], b1pv[t]);
        hdr[1596 + t] = pkh(b2mm[t], b2pv[t]);
        hdr[2324 + t] = pkh(dbm[t], dbp[t]);
    }
    for (int e = t; e < 700; e += 256)
        hdr[1624 + e] = pkh(dwm[e], dwp[e]);
    float* alpha = (float*)(hdr + 2352);
    for (int col = t; col < COLW; col += 256) {
        int imin = (col > 255) ? ((col - 254) >> 1) : 0;
        int imax = min(27, col >> 1);
        alpha[col] = 1.0f / (float)(imax - imin + 1);
    }
}

// ---------------- KF: fused conv1x1 x2 + dwconv5 + sigmoid + emb + where ----------------
// Tile: 8 rows x 16 cols interior, 12 x 20 halo; all 28 channels; t and m1 live in LDS only.
#define TPL 252   // t plane words: 12*21
#define MPL 136   // m1 plane words: 8*17

// load halo col HC (rows row..row+4) into window slot S
#define LOADC(S, HC) do { \
    W##S##0 = tp[(HC)];      W##S##1 = tp[21 + (HC)]; W##S##2 = tp[42 + (HC)]; \
    W##S##3 = tp[63 + (HC)]; W##S##4 = tp[84 + (HC)]; \
} while(0)

// 25 taps: window cols (dc=0..4) in slots S0..S4; weight wv[dy*5+dc]
#define TAPC(S0,S1,S2,S3,S4) \
    pkfma16v(acc, wv[0],  W##S0##0); pkfma16v(acc, wv[5],  W##S0##1); pkfma16v(acc, wv[10], W##S0##2); \
    pkfma16v(acc, wv[15], W##S0##3); pkfma16v(acc, wv[20], W##S0##4); \
    pkfma16v(acc, wv[1],  W##S1##0); pkfma16v(acc, wv[6],  W##S1##1); pkfma16v(acc, wv[11], W##S1##2); \
    pkfma16v(acc, wv[16], W##S1##3); pkfma16v(acc, wv[21], W##S1##4); \
    pkfma16v(acc, wv[2],  W##S2##0); pkfma16v(acc, wv[7],  W##S2##1); pkfma16v(acc, wv[12], W##S2##2); \
    pkfma16v(acc, wv[17], W##S2##3); pkfma16v(acc, wv[22], W##S2##4); \
    pkfma16v(acc, wv[3],  W##S3##0); pkfma16v(acc, wv[8],  W##S3##1); pkfma16v(acc, wv[13], W##S3##2); \
    pkfma16v(acc, wv[18], W##S3##3); pkfma16v(acc, wv[23], W##S3##4); \
    pkfma16v(acc, wv[4],  W##S4##0); pkfma16v(acc, wv[9],  W##S4##1); pkfma16v(acc, wv[14], W##S4##2); \
    pkfma16v(acc, wv[19], W##S4##3); pkfma16v(acc, wv[24], W##S4##4);

// two output cols JA, JB=JA+1; window slots for each; results packed into Z##ZI / Pv##ZI
#define CPAIR(JA, JB, A0,A1,A2,A3,A4, B0,B1,B2,B3,B4, ZI) do { \
    LOADC(A4, (JA) + 4); \
    unsigned int acc = dbc; \
    TAPC(A0,A1,A2,A3,A4) \
    unsigned int accA = acc; \
    LOADC(B4, (JA) + 5); \
    acc = dbc; \
    TAPC(B0,B1,B2,B3,B4) \
    unsigned int muA = mp[JA], muB = mp[JB]; \
    float amA = h2f_lo(accA), apA = h2f_hi(accA); \
    float amB = h2f_lo(acc),  apB = h2f_hi(acc); \
    float atmA = __builtin_amdgcn_rcpf(1.f + __expf(-amA)); \
    float atpA = __builtin_amdgcn_rcpf(1.f + __expf(-apA)); \
    float atmB = __builtin_amdgcn_rcpf(1.f + __expf(-amB)); \
    float atpB = __builtin_amdgcn_rcpf(1.f + __expf(-apB)); \
    float m1mA = h2f_lo(muA), m1pA = h2f_hi(muA); \
    float m1mB = h2f_lo(muB), m1pB = h2f_hi(muB); \
    float emA = fmaf(m1mA, atmA, m1mA); \
    float epA = fmaf(m1pA, atpA, m1pA); \
    float emB = fmaf(m1mB, atmB, m1mB); \
    float epB = fmaf(m1pB, atpB, m1pB); \
    if (emA == 0.f) emA = 1e-6f; \
    if (epA == 0.f) epA = 1e-6f; \
    if (emB == 0.f) emB = 1e-6f; \
    if (epB == 0.f) epB = 1e-6f; \
    Z##ZI  = pk2(x##JA * emA, x##JB * emB); \
    Pv##ZI = pk2(epA, epB); \
} while(0)

__global__ __launch_bounds__(256, 3) void kf_fused(
    const float* __restrict__ Phi, const float* __restrict__ x_pre,
    const unsigned int* __restrict__ hdr,
    bf16* __restrict__ z, bf16* __restrict__ philpv)
{
    __shared__ unsigned int st_t[NC * TPL];   // 28*252*4 = 28,224 B
    __shared__ unsigned int st_m[NC * MPL];   // 28*136*4 = 15,232 B

    int tid = threadIdx.x;
    int bid = blockIdx.x;
    int b  = bid >> 9;           // 32*16 = 512 tiles per batch
    int rt = (bid >> 4) & 31;
    int ct = bid & 15;
    int r0 = rt * 8, c0 = ct * 16;

    const unsigned int* w1h = hdr;
    const unsigned int* w2h = hdr + 784;
    const unsigned int* b1h = hdr + 1568;
    const unsigned int* b2h = hdr + 1596;

    // ---------- phase 1: conv1x1 x2 for the 12x20 halo tile ----------
    if (tid < 240) {
        int r   = tid / 20;          // 0..11
        int col = tid - r * 20;      // 0..19
        int gr = r0 - 2 + r;
        int gc = c0 - 2 + col;
        int tbase = r * 21 + col;
        if ((unsigned)gr < 256u && (unsigned)gc < 256u) {
            const float* phi = Phi + (size_t)b * NC * HW + (size_t)gr * 256 + gc;
#define DECL_P(i) float P##i = phi[(size_t)(i) * HW];
            REP28A(DECL_P)
#undef DECL_P
#define DECL_M(i) unsigned int M##i = b1h[i];
            REP28A(DECL_M)
#undef DECL_M
#define FMA_M1(i) pkfma16(M##i, wr1_[i], pp_);
#define S1C(c) { unsigned int pp_ = pkh(P##c, P##c); \
                 const unsigned int* wr1_ = w1h + (c) * NC; \
                 REP28A(FMA_M1) }
            REP28B(S1C)
#undef S1C
#undef FMA_M1
            // stage 2 -> t tile (LDS)
            for (int o = 0; o < NC; o++) {
                const unsigned int* wr2_ = w2h + o * NC;
                unsigned int T = b2h[o];
#define FMA_T(i) pkfma16(T, wr2_[i], M##i);
                REP28A(FMA_T)
#undef FMA_T
                st_t[o * TPL + tbase] = T;
            }
            // m1 -> LDS (interior px only)
            if (r >= 2 && r < 10 && col >= 2 && col < 18) {
                int mb = (r - 2) * 17 + (col - 2);
#define ST_M(i) st_m[(i) * MPL + mb] = M##i;
                REP28A(ST_M)
#undef ST_M
            }
        } else {
            for (int o = 0; o < NC; o++) st_t[o * TPL + tbase] = 0u;
        }
    }

    __syncthreads();

    // ---------- phase 2: dwconv5 + sigmoid + emb; thread = (channel, row) ----------
    int c   = tid >> 3;      // 0..31 (use < 28)
    int row = tid & 7;       // interior row 0..7
    if (c < NC) {
        unsigned int wv[25];
#pragma unroll
        for (int k = 0; k < 25; k++) wv[k] = hdr[1624 + c * 25 + k];
        unsigned int dbc = hdr[2324 + c];

        const unsigned int* tp = st_t + c * TPL + row * 21;   // window rows row..row+4
        const unsigned int* mp = st_m + c * MPL + row * 17;

        size_t cbase = ((size_t)b * NC + c) * HW;
        size_t goff = cbase + (size_t)(r0 + row) * 256 + c0;
        const float* xr = x_pre + goff;
        float4 Xa = *reinterpret_cast<const float4*>(xr);
        float4 Xb = *reinterpret_cast<const float4*>(xr + 4);
        float4 Xc = *reinterpret_cast<const float4*>(xr + 8);
        float4 Xd = *reinterpret_cast<const float4*>(xr + 12);
        float x0 = Xa.x,  x1 = Xa.y,  x2 = Xa.z,  x3 = Xa.w;
        float x4 = Xb.x,  x5 = Xb.y,  x6 = Xb.z,  x7 = Xb.w;
        float x8 = Xc.x,  x9 = Xc.y,  x10 = Xc.z, x11 = Xc.w;
        float x12 = Xd.x, x13 = Xd.y, x14 = Xd.z, x15 = Xd.w;

        unsigned int W00,W01,W02,W03,W04, W10,W11,W12,W13,W14, W20,W21,W22,W23,W24,
                     W30,W31,W32,W33,W34, W40,W41,W42,W43,W44;
        unsigned int Z0,Z1,Z2,Z3,Z4,Z5,Z6,Z7, Pv0,Pv1,Pv2,Pv3,Pv4,Pv5,Pv6,Pv7;

        LOADC(0, 0); LOADC(1, 1); LOADC(2, 2); LOADC(3, 3);
        CPAIR(0, 1,   0,1,2,3,4,  1,2,3,4,0, 0);
        CPAIR(2, 3,   2,3,4,0,1,  3,4,0,1,2, 1);
        CPAIR(4, 5,   4,0,1,2,3,  0,1,2,3,4, 2);
        CPAIR(6, 7,   1,2,3,4,0,  2,3,4,0,1, 3);
        CPAIR(8, 9,   3,4,0,1,2,  4,0,1,2,3, 4);
        CPAIR(10, 11, 0,1,2,3,4,  1,2,3,4,0, 5);
        CPAIR(12, 13, 2,3,4,0,1,  3,4,0,1,2, 6);
        CPAIR(14, 15, 4,0,1,2,3,  0,1,2,3,4, 7);

        *reinterpret_cast<uint4*>(z + goff)          = make_uint4(Z0, Z1, Z2, Z3);
        *reinterpret_cast<uint4*>(z + goff + 8)      = make_uint4(Z4, Z5, Z6, Z7);
        *reinterpret_cast<uint4*>(philpv + goff)     = make_uint4(Pv0, Pv1, Pv2, Pv3);
        *reinterpret_cast<uint4*>(philpv + goff + 8) = make_uint4(Pv4, Pv5, Pv6, Pv7);
    }
}

// ---------------- K3: temp = alpha * (y - A_op partial sums) ----------------
__global__ void k3_aop(const float* __restrict__ y, const bf16* __restrict__ z,
                       const float* __restrict__ alpha, float* __restrict__ temp)
{
    int idx = blockIdx.x * 256 + threadIdx.x;
    if (idx >= BATCH * ROWW * COLW) return;
    int col = idx % COLW;
    int bh  = idx / COLW;
    int h = bh & 255;
    int b = bh >> 8;
    int imin = (col > 255) ? ((col - 254) >> 1) : 0;
    int imax = min(27, col >> 1);
    float acc = y[idx];
    size_t base = (size_t)b * NC * HW + (size_t)h * 256 + col;
    for (int i = imin; i <= imax; i++) {
        acc -= __bfloat162float(z[base + (size_t)i * (HW - 2)]);
    }
    temp[idx] = acc * alpha[col];
}

// ---------------- K4: out = x_pre + delta * temp_gathered * PhiL_pv ----------------
__global__ void k4_out(const float* __restrict__ x_pre, const bf16* __restrict__ philpv,
                       const float* __restrict__ temp, const float* __restrict__ delta,
                       float* __restrict__ out)
{
    int idx4 = blockIdx.x * 256 + threadIdx.x;   // quad index; exact grid
    int wq4 = idx4 & 63;
    int rest = idx4 >> 6;
    int h = rest & 255; rest >>= 8;
    int i = rest % NC;
    int b = rest / NC;
    int w = wq4 * 4;
    int col = w + 2 * i;
    const float* trow = temp + ((size_t)(b * 256 + h)) * COLW + col;
    float t0 = trow[0], t1 = trow[1], t2 = trow[2], t3 = trow[3];
    size_t off = ((size_t)(b * NC + i)) * HW + (size_t)(h * 256 + w);
    uint2 pu = *reinterpret_cast<const uint2*>(philpv + off);
    float4 xp = *reinterpret_cast<const float4*>(x_pre + off);
    float d = delta[0];
    float4 o4;
    o4.x = fmaf(d * t0, bflo(pu.x), xp.x);
    o4.y = fmaf(d * t1, bfhi(pu.x), xp.y);
    o4.z = fmaf(d * t2, bflo(pu.y), xp.z);
    o4.w = fmaf(d * t3, bfhi(pu.y), xp.w);
    *reinterpret_cast<float4*>(out + off) = o4;
}

// ---------------- launch ----------------
extern "C" void kernel_launch(void* const* d_in, const int* in_sizes, int n_in,
                              void* d_out, int out_size, void* d_ws, size_t ws_size,
                              hipStream_t stream)
{
    const float* y     = (const float*)d_in[0];
    const float* Phi   = (const float*)d_in[1];
    const float* x_pre = (const float*)d_in[2];
    const float* delta = (const float*)d_in[3];
    const float* mm_w1 = (const float*)d_in[4];
    const float* mm_b1 = (const float*)d_in[5];
    const float* mm_w2 = (const float*)d_in[6];
    const float* mm_b2 = (const float*)d_in[7];
    const float* mm_dw = (const float*)d_in[8];
    const float* mm_db = (const float*)d_in[9];
    const float* pv_w1 = (const float*)d_in[10];
    const float* pv_b1 = (const float*)d_in[11];
    const float* pv_w2 = (const float*)d_in[12];
    const float* pv_b2 = (const float*)d_in[13];
    const float* pv_dw = (const float*)d_in[14];
    const float* pv_db = (const float*)d_in[15];
    float* out = (float*)d_out;

    char* ws = (char*)d_ws;
    const size_t A = (size_t)BATCH * NC * HW * 4;   // 117,440,512 B
    unsigned int* hdr    = (unsigned int*)ws;
    bf16*         zz     = (bf16*)(ws + HDR_BYTES);
    bf16*         philpv = (bf16*)(ws + HDR_BYTES + A / 2);
    float*        temp   = (float*)(ws + HDR_BYTES + A);
    const float*  alpha  = (const float*)(ws + 2352 * 4);

    k0_prep<<<1, 256, 0, stream>>>(mm_w1, pv_w1, mm_w2, pv_w2,
                                   mm_b1, pv_b1, mm_b2, pv_b2,
                                   mm_dw, pv_dw, mm_db, pv_db, hdr);
    kf_fused<<<BATCH * 32 * 16, 256, 0, stream>>>(Phi, x_pre, hdr, zz, philpv);
    k3_aop<<<(BATCH * ROWW * COLW + 255) / 256, 256, 0, stream>>>(y, zz, alpha, temp);
    k4_out<<<(BATCH * NC * HW / 4) / 256, 256, 0, stream>>>(x_pre, philpv, temp, delta, out);
}

// Round 15
// 258.177 us; speedup vs baseline: 1.1495x; 1.1495x over previous
//
#include <hip/hip_runtime.h>
#include <hip/hip_bf16.h>
#include <cstdint>

#define NC 28
#define HW 65536   // 256*256
#define ROWW 256
#define COLW 310
#define BATCH 16

typedef __hip_bfloat16 bf16;

__device__ __forceinline__ unsigned int pkh(float lo, float hi) {
    auto h = __builtin_amdgcn_cvt_pkrtz(lo, hi);
    return __builtin_bit_cast(unsigned int, h);
}
__device__ __forceinline__ float h2f_lo(unsigned int u) {
    return (float)__builtin_bit_cast(_Float16, (unsigned short)(u & 0xffffu));
}
__device__ __forceinline__ float h2f_hi(unsigned int u) {
    return (float)__builtin_bit_cast(_Float16, (unsigned short)(u >> 16));
}
__device__ __forceinline__ float h2f(unsigned short u) {
    return (float)__builtin_bit_cast(_Float16, u);
}
// packed 2xf16 fma: acc = w*x + acc (w in SGPR, block-uniform)
__device__ __forceinline__ void pkfma16(unsigned int& acc, unsigned int w, unsigned int x) {
    asm("v_pk_fma_f16 %0, %1, %2, %0" : "+v"(acc) : "s"(w), "v"(x));
}

#define REP28A(X) X(0) X(1) X(2) X(3) X(4) X(5) X(6) X(7) X(8) X(9) X(10) X(11) X(12) X(13) \
                  X(14) X(15) X(16) X(17) X(18) X(19) X(20) X(21) X(22) X(23) X(24) X(25) X(26) X(27)

// hdr layout (uint words):
//   [0..783]     w1h[c*28+o]  f16 pair (mm,pv)  (transposed)
//   [784..1567]  w2h[o*28+m]
//   [1568..1595] b1h[o]
//   [1596..1623] b2h[o]
//   [1624..2323] dwh[c*25+k]
//   [2324..2351] dbh[c]
//   [2352..2661] alpha[col] (float bits)
#define HDR_BYTES 16384

// ---------------- K0: prep ----------------
__global__ void k0_prep(const float* __restrict__ w1mm, const float* __restrict__ w1pv,
                        const float* __restrict__ w2mm, const float* __restrict__ w2pv,
                        const float* __restrict__ b1mm, const float* __restrict__ b1pv,
                        const float* __restrict__ b2mm, const float* __restrict__ b2pv,
                        const float* __restrict__ dwm,  const float* __restrict__ dwp,
                        const float* __restrict__ dbm,  const float* __restrict__ dbp,
                        unsigned int* __restrict__ hdr)
{
    int t = threadIdx.x;
    for (int e = t; e < 784; e += 256) {
        int c = e / 28, o = e - c * 28;
        hdr[e]       = pkh(w1mm[o * 28 + c], w1pv[o * 28 + c]);
        hdr[784 + e] = pkh(w2mm[e], w2pv[e]);
    }
    if (t < 28) {
        hdr[1568 + t] = pkh(b1mm[t], b1pv[t]);
        hdr[1596 + t] = pkh(b2mm[t], b2pv[t]);
        hdr[2324 + t] = pkh(dbm[t], dbp[t]);
    }
    for (int e = t; e < 700; e += 256)
        hdr[1624 + e] = pkh(dwm[e], dwp[e]);
    float* alpha = (float*)(hdr + 2352);
    for (int col = t; col < COLW; col += 256) {
        int imin = (col > 255) ? ((col - 254) >> 1) : 0;
        int imax = min(27, col >> 1);
        alpha[col] = 1.0f / (float)(imax - imin + 1);
    }
}

// ---------------- K1: conv1x1 x2 both branches; f16 packed math, 4 px/thread ----------------
__global__ __launch_bounds__(256, 3) void k1_conv1x1(
    const float* __restrict__ Phi, const unsigned int* __restrict__ hdr,
    unsigned int* __restrict__ t_pk, unsigned int* __restrict__ m1_pk)
{
    int idx = blockIdx.x * 256 + threadIdx.x;   // pixel-quad index
    int b   = idx >> 14;                        // 16384 quads per batch
    int hw4 = (idx & 16383) << 2;
    const float* phi = Phi + (size_t)b * NC * HW + hw4;
    const unsigned int* w1h = hdr;              // [c*28+o]
    const unsigned int* w2h = hdr + 784;        // [o*28+m]
    const unsigned int* b1h = hdr + 1568;
    const unsigned int* b2h = hdr + 1596;

#define DECL_M(i) unsigned int MA##i = b1h[i], MB##i = MA##i, MC##i = MA##i, MD##i = MA##i;
    REP28A(DECL_M)
#undef DECL_M

    for (int c = 0; c < NC; c++) {
        float4 P = *reinterpret_cast<const float4*>(phi + (size_t)c * HW);
        unsigned int pa = pkh(P.x, P.x);
        unsigned int pb = pkh(P.y, P.y);
        unsigned int pc = pkh(P.z, P.z);
        unsigned int pd = pkh(P.w, P.w);
        const unsigned int* wr1_ = w1h + c * NC;
#define FMA_M(i) pkfma16(MA##i, wr1_[i], pa); pkfma16(MB##i, wr1_[i], pb); \
                 pkfma16(MC##i, wr1_[i], pc); pkfma16(MD##i, wr1_[i], pd);
        REP28A(FMA_M)
#undef FMA_M
    }

    size_t base = (size_t)b * NC * HW + hw4;
#define ST_M(i) *reinterpret_cast<uint4*>(m1_pk + base + (size_t)(i) * HW) = \
    make_uint4(MA##i, MB##i, MC##i, MD##i);
    REP28A(ST_M)
#undef ST_M

    for (int o = 0; o < NC; o++) {
        const unsigned int* wr2_ = w2h + o * NC;
        unsigned int Ta = b2h[o], Tb = Ta, Tc = Ta, Td = Ta;
#define FMA_T(i) pkfma16(Ta, wr2_[i], MA##i); pkfma16(Tb, wr2_[i], MB##i); \
                 pkfma16(Tc, wr2_[i], MC##i); pkfma16(Td, wr2_[i], MD##i);
        REP28A(FMA_T)
#undef FMA_T
        *reinterpret_cast<uint4*>(t_pk + base + (size_t)o * HW) = make_uint4(Ta, Tb, Tc, Td);
    }
}

// ---------------- K2: dwconv5 + sigmoid + emb + where; writes PhiL_mm and PhiL_pv (f16) ----------------
#define TR 16
#define LROW 264   // words per LDS row; interior at [4..259], pads [2,3] and [260,261]

#define LDROW(S, LR) do { \
    const uint2* rp_ = reinterpret_cast<const uint2*>(&st[(LR) * LROW + 2 + cc]); \
    uint2 a_ = rp_[0], b_ = rp_[1], c_ = rp_[2]; \
    W##S##0 = a_.x; W##S##1 = a_.y; W##S##2 = b_.x; \
    W##S##3 = b_.y; W##S##4 = c_.x; W##S##5 = c_.y; \
} while(0)

#define PRE(S, R) do { \
    size_t o_ = cbase + (size_t)(h0 + (R)) * 256 + cc; \
    mu##S = *reinterpret_cast<const uint2*>(m1_pk + o_); \
} while(0)

#define TAPR(S, B) \
    pkfma16(acc0, wq[(B)+0], W##S##0); pkfma16(acc1, wq[(B)+0], W##S##1); \
    pkfma16(acc0, wq[(B)+1], W##S##1); pkfma16(acc1, wq[(B)+1], W##S##2); \
    pkfma16(acc0, wq[(B)+2], W##S##2); pkfma16(acc1, wq[(B)+2], W##S##3); \
    pkfma16(acc0, wq[(B)+3], W##S##3); pkfma16(acc1, wq[(B)+3], W##S##4); \
    pkfma16(acc0, wq[(B)+4], W##S##4); pkfma16(acc1, wq[(B)+4], W##S##5);

#define CROW2(R, PS, S0,S1,S2,S3,S4) do { \
    unsigned int acc0 = dbc, acc1 = dbc; \
    TAPR(S0, 0) TAPR(S1, 5) TAPR(S2, 10) TAPR(S3, 15) TAPR(S4, 20) \
    float am0 = h2f_lo(acc0), ap0 = h2f_hi(acc0); \
    float am1 = h2f_lo(acc1), ap1 = h2f_hi(acc1); \
    float atm0 = __builtin_amdgcn_rcpf(1.f + __expf(-am0)); \
    float atp0 = __builtin_amdgcn_rcpf(1.f + __expf(-ap0)); \
    float atm1 = __builtin_amdgcn_rcpf(1.f + __expf(-am1)); \
    float atp1 = __builtin_amdgcn_rcpf(1.f + __expf(-ap1)); \
    float m1m0 = h2f_lo(mu##PS.x), m1p0 = h2f_hi(mu##PS.x); \
    float m1m1 = h2f_lo(mu##PS.y), m1p1 = h2f_hi(mu##PS.y); \
    float em0 = fmaf(m1m0, atm0, m1m0); \
    float ep0 = fmaf(m1p0, atp0, m1p0); \
    float em1 = fmaf(m1m1, atm1, m1m1); \
    float ep1 = fmaf(m1p1, atp1, m1p1); \
    if (em0 == 0.f) em0 = 1e-6f; \
    if (ep0 == 0.f) ep0 = 1e-6f; \
    if (em1 == 0.f) em1 = 1e-6f; \
    if (ep1 == 0.f) ep1 = 1e-6f; \
    size_t off_ = cbase + (size_t)(h0 + (R)) * 256 + cc; \
    *reinterpret_cast<unsigned int*>(phm + off_) = pkh(em0, em1); \
    *reinterpret_cast<unsigned int*>(php + off_) = pkh(ep0, ep1); \
} while(0)

__global__ __launch_bounds__(256, 4) void k2_attn(
    const unsigned int* __restrict__ t_pk, const unsigned int* __restrict__ m1_pk,
    const unsigned int* __restrict__ hdr,
    unsigned short* __restrict__ phm, unsigned short* __restrict__ php)
{
    __shared__ unsigned int st[(TR + 4) * LROW];   // 21,120 B

    int bid = blockIdx.x;
    int rt = bid & 15;
    int c  = (bid >> 4) % NC;
    int b  = (bid >> 4) / NC;
    int r0 = rt * TR;
    size_t cbase = ((size_t)b * NC + c) * HW;
    int tid = threadIdx.x;
    int lane = tid & 63;
    int wv = tid >> 6;
    int cc = (tid & 127) * 2;        // column pair base
    int half = tid >> 7;             // 0: rows 0..7, 1: rows 8..15
    int lbase = half * 8;
    int h0 = r0 + lbase;

    if (tid < 80) {
        int rr = tid >> 2, jj = tid & 3;
        st[rr * LROW + ((jj < 2) ? 2 + jj : 258 + jj)] = 0u;
    }

#pragma unroll
    for (int j = 0; j < 5; j++) {
        int r = wv * 5 + j;
        int gr = r0 - 2 + r;
        if (gr >= 0 && gr < 256) {
            const unsigned int* gsrc = t_pk + cbase + (size_t)gr * 256 + lane * 4;
            __builtin_amdgcn_global_load_lds(
                (const __attribute__((address_space(1))) unsigned int*)gsrc,
                (__attribute__((address_space(3))) unsigned int*)&st[r * LROW + 4],
                16, 0, 0);
        } else {
            st[r * LROW + 4 + lane]       = 0u;
            st[r * LROW + 4 + 64 + lane]  = 0u;
            st[r * LROW + 4 + 128 + lane] = 0u;
            st[r * LROW + 4 + 192 + lane] = 0u;
        }
    }

    unsigned int wq[25];
#pragma unroll
    for (int k = 0; k < 25; k++)
        wq[k] = __builtin_amdgcn_readfirstlane(hdr[1624 + c * 25 + k]);
    unsigned int dbc = __builtin_amdgcn_readfirstlane(hdr[2324 + c]);

    uint2 mu0, mu1, mu2, mu3, mu4;
    PRE(0, 0); PRE(1, 1); PRE(2, 2); PRE(3, 3);

    __syncthreads();

    unsigned int W00,W01,W02,W03,W04,W05, W10,W11,W12,W13,W14,W15,
                 W20,W21,W22,W23,W24,W25, W30,W31,W32,W33,W34,W35,
                 W40,W41,W42,W43,W44,W45;

    LDROW(0, lbase + 0); LDROW(1, lbase + 1); LDROW(2, lbase + 2); LDROW(3, lbase + 3);
    LDROW(4, lbase + 4);  PRE(4, 4);  CROW2(0, 0, 0,1,2,3,4);
    LDROW(0, lbase + 5);  PRE(0, 5);  CROW2(1, 1, 1,2,3,4,0);
    LDROW(1, lbase + 6);  PRE(1, 6);  CROW2(2, 2, 2,3,4,0,1);
    LDROW(2, lbase + 7);  PRE(2, 7);  CROW2(3, 3, 3,4,0,1,2);
    LDROW(3, lbase + 8);              CROW2(4, 4, 4,0,1,2,3);
    LDROW(4, lbase + 9);              CROW2(5, 0, 0,1,2,3,4);
    LDROW(0, lbase + 10);             CROW2(6, 1, 1,2,3,4,0);
    LDROW(1, lbase + 11);             CROW2(7, 2, 2,3,4,0,1);
}

// ---------------- K34: fused A_op-residual + A_pinv + output; one block per (b,h) row ----------------
// Pass 1: each thread owns output column(s) -> PRIVATE register accumulation (no LDS RMW, no race).
__global__ __launch_bounds__(256, 8) void k34_out(
    const float* __restrict__ y, const float* __restrict__ x_pre,
    const unsigned short* __restrict__ phm, const unsigned short* __restrict__ php,
    const unsigned int* __restrict__ hdr, const float* __restrict__ delta,
    float* __restrict__ out)
{
    __shared__ float temp[312];

    int tid = threadIdx.x;
    int b = blockIdx.x >> 8;
    int h = blockIdx.x & 255;
    const float* alpha = (const float*)(hdr + 2352);
    size_t rowbase = ((size_t)b * NC) * HW + (size_t)h * 256;   // + i*HW + w
    const float* yr = y + ((size_t)b * 256 + h) * COLW;

    // pass 1: temp[col] = alpha * (y[col] - sum_i x_pre[i][col-2i] * em[i][col-2i])
    for (int col = tid; col < COLW; col += 256) {
        int imin = (col > 255) ? ((col - 254) >> 1) : 0;
        int imax = min(27, col >> 1);
        float acc = yr[col];
        size_t off = rowbase + (size_t)imin * (HW - 2) + col;   // i*HW + (col-2i)
        for (int i = imin; i <= imax; i++) {
            acc -= x_pre[off] * h2f(phm[off]);
            off += (HW - 2);
        }
        temp[col] = acc * alpha[col];
    }
    __syncthreads();

    // pass 2: out[i][w] = x_pre + delta * temp[w+2i] * ep
    float d = delta[0];
    for (int i = 0; i < NC; i++) {
        size_t off = rowbase + (size_t)i * HW + tid;
        out[off] = fmaf(d * temp[tid + 2 * i], h2f(php[off]), x_pre[off]);
    }
}

// ---------------- launch ----------------
extern "C" void kernel_launch(void* const* d_in, const int* in_sizes, int n_in,
                              void* d_out, int out_size, void* d_ws, size_t ws_size,
                              hipStream_t stream)
{
    const float* y     = (const float*)d_in[0];
    const float* Phi   = (const float*)d_in[1];
    const float* x_pre = (const float*)d_in[2];
    const float* delta = (const float*)d_in[3];
    const float* mm_w1 = (const float*)d_in[4];
    const float* mm_b1 = (const float*)d_in[5];
    const float* mm_w2 = (const float*)d_in[6];
    const float* mm_b2 = (const float*)d_in[7];
    const float* mm_dw = (const float*)d_in[8];
    const float* mm_db = (const float*)d_in[9];
    const float* pv_w1 = (const float*)d_in[10];
    const float* pv_b1 = (const float*)d_in[11];
    const float* pv_w2 = (const float*)d_in[12];
    const float* pv_b2 = (const float*)d_in[13];
    const float* pv_dw = (const float*)d_in[14];
    const float* pv_db = (const float*)d_in[15];
    float* out = (float*)d_out;

    char* ws = (char*)d_ws;
    const size_t A = (size_t)BATCH * NC * HW * 4;   // 117,440,512 B
    unsigned int*   hdr   = (unsigned int*)ws;
    unsigned int*   t_pk  = (unsigned int*)(ws + HDR_BYTES);
    unsigned int*   m1_pk = (unsigned int*)(ws + HDR_BYTES + A);
    unsigned short* phm   = (unsigned short*)(ws + HDR_BYTES + 2 * A);
    unsigned short* php   = (unsigned short*)(ws + HDR_BYTES + 2 * A + A / 2);

    k0_prep<<<1, 256, 0, stream>>>(mm_w1, pv_w1, mm_w2, pv_w2,
                                   mm_b1, pv_b1, mm_b2, pv_b2,
                                   mm_dw, pv_dw, mm_db, pv_db, hdr);
    k1_conv1x1<<<1024, 256, 0, stream>>>(Phi, hdr, t_pk, m1_pk);
    k2_attn<<<BATCH * NC * 16, 256, 0, stream>>>(t_pk, m1_pk, hdr, phm, php);
    k34_out<<<BATCH * 256, 256, 0, stream>>>(y, x_pre, phm, php, hdr, delta, out);
}